// Round 8
// baseline (423.591 us; speedup 1.0000x reference)
//
#include <hip/hip_runtime.h>
#include <hip/hip_bf16.h>

typedef unsigned short u16;
typedef unsigned int u32;
typedef short s16x8 __attribute__((ext_vector_type(8)));
typedef float f32x4 __attribute__((ext_vector_type(4)));
typedef u16 u16x4 __attribute__((ext_vector_type(4)));
typedef u32 u32x2 __attribute__((ext_vector_type(2)));

#define D_MODEL 1024
#define NHEAD 16
#define DK 64
#define B_ 4
#define N_ 2048
#define M_TOT (B_ * N_) /* 8192 */
#define QBLK 64   /* per block; 16 q-rows per wave */
#define KVBLK 64
#define SCALE2 0.1803368801111137f /* 0.125 * log2(e) */

__device__ __forceinline__ u16 f2b(float x) {
  __hip_bfloat16 h = __float2bfloat16(x);
  return __builtin_bit_cast(u16, h);
}

__device__ __forceinline__ void gload_lds16(const void* gp, void* lp) {
  __builtin_amdgcn_global_load_lds(
      (const __attribute__((address_space(1))) unsigned int*)gp,
      (__attribute__((address_space(3))) unsigned int*)lp, 16, 0, 0);
}

// ---------------- elementwise f32 -> bf16 ----------------
__global__ __launch_bounds__(256) void cvt_f32_bf16(const float* __restrict__ x,
                                                    u16* __restrict__ y, int n4) {
  int i = blockIdx.x * 256 + threadIdx.x;
  if (i < n4) {
    f32x4 v = *(const f32x4*)(x + (size_t)i * 4);
    u16x4 o;
    o[0] = f2b(v[0]); o[1] = f2b(v[1]); o[2] = f2b(v[2]); o[3] = f2b(v[3]);
    *(u16x4*)(y + (size_t)i * 4) = o;
  }
}

// ---------------- padding mask -> float bias (0 or -inf) ----------------
__global__ __launch_bounds__(256) void mask_bias(const int* __restrict__ mask,
                                                 float* __restrict__ Mb, int n) {
  int i = blockIdx.x * 256 + threadIdx.x;
  if (i < n) Mb[i] = mask[i] ? 0.f : -INFINITY;
}

// ---------------- W (f32, [K][N]) -> W^T (bf16, [N][K]) ----------------
__global__ __launch_bounds__(256) void wtrans(const float* __restrict__ W,
                                              u16* __restrict__ Wt) {
  __shared__ float tile[32][33];
  int bi = blockIdx.y, bj = blockIdx.x;
  int tx = threadIdx.x & 31, ty = threadIdx.x >> 5; // 32 x 8
#pragma unroll
  for (int r = 0; r < 4; ++r)
    tile[ty + r * 8][tx] = W[(size_t)(bi * 32 + ty + r * 8) * D_MODEL + bj * 32 + tx];
  __syncthreads();
#pragma unroll
  for (int r = 0; r < 4; ++r)
    Wt[(size_t)(bj * 32 + ty + r * 8) * D_MODEL + bi * 32 + tx] = f2b(tile[tx][ty + r * 8]);
}

// ------------- V [B,N,H*64] bf16 -> Vt [B,H,64,N] bf16 -------------
__global__ __launch_bounds__(256) void vtrans(const u16* __restrict__ Vp,
                                              u16* __restrict__ Vt) {
  __shared__ u16 tile[64][65];
  int n0 = blockIdx.x * 64, h = blockIdx.y, b = blockIdx.z;
  int tx = threadIdx.x & 63, ty = threadIdx.x >> 6;
  for (int r = ty; r < 64; r += 4)
    tile[r][tx] = Vp[(size_t)(b * N_ + n0 + r) * D_MODEL + h * DK + tx];
  __syncthreads();
  for (int r = ty; r < 64; r += 4)
    Vt[((size_t)(b * NHEAD + h) * DK + r) * N_ + n0 + tx] = tile[tx][r];
}

// ------------- GEMM: C[M,N] = A[M,K](bf16) * Bt[N,K](bf16)^T -------------
template <bool OUT_F32>
__global__ __launch_bounds__(256) void gemm_bt(const u16* __restrict__ A,
                                               const u16* __restrict__ Bt,
                                               float* __restrict__ Cf,
                                               u16* __restrict__ Cb,
                                               int M, int N, int K) {
  __shared__ __align__(16) u16 Atile[128 * 32];
  __shared__ __align__(16) u16 Btile[128 * 32];
  int tid = threadIdx.x;
  int w = tid >> 6, lane = tid & 63;
  int g = lane >> 4, c = lane & 15;
  int wr = w >> 1, wc = w & 1;
  int bi = blockIdx.y, bj = blockIdx.x;
  const int rowA0 = bi * 128, rowB0 = bj * 128;

  const f32x4 fzero = {0.f, 0.f, 0.f, 0.f};
  f32x4 acc[4][4];
#pragma unroll
  for (int m = 0; m < 4; ++m)
#pragma unroll
    for (int n = 0; n < 4; ++n) acc[m][n] = fzero;

  for (int k0 = 0; k0 < K; k0 += 32) {
#pragma unroll
    for (int cc = 0; cc < 2; ++cc) {
      int li = w * 2 + cc;
      const u16* ga = A + (size_t)(rowA0 + li * 16 + (lane >> 2)) * K + k0 + (lane & 3) * 8;
      gload_lds16(ga, &Atile[li * 512]);
      const u16* gb = Bt + (size_t)(rowB0 + li * 16 + (lane >> 2)) * K + k0 + (lane & 3) * 8;
      gload_lds16(gb, &Btile[li * 512]);
    }
    __syncthreads();
    s16x8 af[4], bfr[4];
#pragma unroll
    for (int m = 0; m < 4; ++m)
      af[m] = *(const s16x8*)&Atile[(wr * 64 + m * 16 + c) * 32 + g * 8];
#pragma unroll
    for (int n = 0; n < 4; ++n)
      bfr[n] = *(const s16x8*)&Btile[(wc * 64 + n * 16 + c) * 32 + g * 8];
#pragma unroll
    for (int m = 0; m < 4; ++m)
#pragma unroll
      for (int n = 0; n < 4; ++n)
        acc[m][n] = __builtin_amdgcn_mfma_f32_16x16x32_bf16(af[m], bfr[n], acc[m][n], 0, 0, 0);
    __syncthreads();
  }
#pragma unroll
  for (int m = 0; m < 4; ++m)
#pragma unroll
    for (int n = 0; n < 4; ++n)
#pragma unroll
      for (int r = 0; r < 4; ++r) {
        int row = rowA0 + wr * 64 + m * 16 + g * 4 + r;
        int col = rowB0 + wc * 64 + n * 16 + c;
        size_t idx = (size_t)row * N + col;
        if (OUT_F32) Cf[idx] = acc[m][n][r];
        else Cb[idx] = f2b(acc[m][n][r]);
      }
}

// ------------- causal flash attention, swapped QK^T, pipelined ------------
// QBLK=64 (16 q/wave), 1024 blocks: XCD-local heads, paired q-tiles
// {31-p, p} -> every wave does exactly qt+1 tiles, block total = 33 steps.
// K reg double-buffer prefetch; V issued at tile top; no __syncthreads.
__global__ __launch_bounds__(256) void attn_fwd(const u16* __restrict__ Qp,
                                                const u16* __restrict__ Kp,
                                                const u16* __restrict__ Vt,
                                                const float* __restrict__ Mb,
                                                u16* __restrict__ Out) {
  __shared__ __align__(16) u16 Plds[4][16 * KVBLK];
  // 1024 blocks: xcd = bid&7 owns heads [xcd*8, xcd*8+8); p -> {31-p, p}
  int bid = blockIdx.x;
  int xcd = bid & 7;
  int inner = bid >> 3;  // 0..127
  int j = inner >> 4;    // head-within-XCD 0..7
  int pair = inner & 15; // 0..15
  int bh = xcd * 8 + j;  // 0..63
  int b = bh >> 4, h = bh & 15;
  int tid = threadIdx.x, w = tid >> 6, lane = tid & 63;
  int g = lane >> 4, c = lane & 15;

  const u16* kbase = Kp + (size_t)b * N_ * D_MODEL + h * DK;
  const u16* vbase = Vt + (size_t)(b * NHEAD + h) * DK * N_;
  const float* mp0 = Mb + (size_t)b * N_;

  const f32x4 fzero = {0.f, 0.f, 0.f, 0.f};
  int sw = (c & 7) << 4;
  u16* Pw = &Plds[w][0];

#pragma unroll 1
  for (int ph = 0; ph < 2; ++ph) {
    int qt = ph ? pair : 31 - pair;
    int q0 = qt * QBLK;
    int wq0 = q0 + w * 16; // this wave's first q row
    int ntw = qt + 1;      // uniform across the block's waves

    // Q fragments (B-operand): lane holds Q[wq0+c][kh*32+g*8+e]
    s16x8 qf[2];
    {
      const u16* qb2 = Qp + (size_t)(b * N_ + wq0 + c) * D_MODEL + h * DK;
      qf[0] = *(const s16x8*)(qb2 + g * 8);
      qf[1] = *(const s16x8*)(qb2 + 32 + g * 8);
    }

    f32x4 oacc[4];
#pragma unroll
    for (int d = 0; d < 4; ++d) oacc[d] = fzero;
    float mr = -1e30f, lr = 0.f;

    auto loadk = [&](s16x8(&kf)[4][2], int t) {
      int kv0 = t * KVBLK;
#pragma unroll
      for (int n = 0; n < 4; ++n) {
        const u16* kr = &kbase[(size_t)(kv0 + n * 16 + c) * D_MODEL + g * 8];
        kf[n][0] = *(const s16x8*)kr;
        kf[n][1] = *(const s16x8*)(kr + 32);
      }
    };

    auto step = [&](s16x8(&kc)[4][2], s16x8(&kn)[4][2], int t) {
      int kv0 = t * KVBLK;
      // prefetch next K tile into the other reg bank (hidden by this tile)
      if (t + 1 < ntw) loadk(kn, t + 1);
      // V fragments for THIS tile issued up front (consumed late)
      s16x8 vf[2][4];
#pragma unroll
      for (int ks = 0; ks < 2; ++ks)
#pragma unroll
        for (int d = 0; d < 4; ++d)
          vf[ks][d] = *(const s16x8*)&vbase[(size_t)(d * 16 + c) * N_ + kv0 + ks * 32 + g * 8];
      f32x4 mbv[4];
#pragma unroll
      for (int n = 0; n < 4; ++n) mbv[n] = *(const f32x4*)&mp0[kv0 + n * 16 + g * 4];

      // ---- S^T = K Q^T : st[n][r] = S[q=wq0+c][kv=kv0+n*16+g*4+r]
      f32x4 st[4];
#pragma unroll
      for (int n = 0; n < 4; ++n) {
        f32x4 acc = __builtin_amdgcn_mfma_f32_16x16x32_bf16(kc[n][0], qf[0], fzero, 0, 0, 0);
        st[n] = __builtin_amdgcn_mfma_f32_16x16x32_bf16(kc[n][1], qf[1], acc, 0, 0, 0);
      }

      // ---- scale + padding bias + causal mask, per-lane row max
      bool diag = (kv0 + KVBLK - 1 > wq0);
      int qq = wq0 + c;
#pragma unroll
      for (int n = 0; n < 4; ++n)
#pragma unroll
        for (int r = 0; r < 4; ++r) {
          float v = fmaf(st[n][r], SCALE2, mbv[n][r]);
          if (diag) {
            int kv = kv0 + n * 16 + g * 4 + r;
            v = (kv > qq) ? -INFINITY : v;
          }
          st[n][r] = v;
        }
      float m0 = fmaxf(fmaxf(st[0][0], st[0][1]), fmaxf(st[0][2], st[0][3]));
      float m1 = fmaxf(fmaxf(st[1][0], st[1][1]), fmaxf(st[1][2], st[1][3]));
      float m2 = fmaxf(fmaxf(st[2][0], st[2][1]), fmaxf(st[2][2], st[2][3]));
      float m3 = fmaxf(fmaxf(st[3][0], st[3][1]), fmaxf(st[3][2], st[3][3]));
      float pm = fmaxf(fmaxf(m0, m1), fmaxf(m2, m3));
      pm = fmaxf(pm, __shfl_xor(pm, 16));
      pm = fmaxf(pm, __shfl_xor(pm, 32));

      // ---- defer-max rescale (T13)
      if (__any(pm > mr + 8.f)) {
        float mnew = fmaxf(mr, pm);
        float al = exp2f(mr - mnew);
        mr = mnew;
        lr *= al;
        float alT[4];
#pragma unroll
        for (int r = 0; r < 4; ++r) alT[r] = __shfl(al, (g << 2) + r);
#pragma unroll
        for (int d = 0; d < 4; ++d)
#pragma unroll
          for (int r = 0; r < 4; ++r) oacc[d][r] *= alT[r];
      }

      // ---- p = exp2(s - m), row sum, P -> wave-private LDS (swizzled)
      float rs = 0.f;
#pragma unroll
      for (int n = 0; n < 4; ++n) {
#pragma unroll
        for (int r = 0; r < 4; ++r) {
          float p = exp2f(st[n][r] - mr);
          st[n][r] = p;
          rs += p;
        }
        u32 lo = (u32)f2b(st[n][0]) | ((u32)f2b(st[n][1]) << 16);
        u32 hi = (u32)f2b(st[n][2]) | ((u32)f2b(st[n][3]) << 16);
        u32x2 pv = {lo, hi};
        *(u32x2*)&Pw[c * DK + (((n * 32 + g * 8) ^ sw) >> 1)] = pv;
      }
      rs += __shfl_xor(rs, 16);
      rs += __shfl_xor(rs, 32);
      lr += rs;

      // ---- O += P * V
#pragma unroll
      for (int ks = 0; ks < 2; ++ks) {
        int co = ((ks * 64 + g * 16) ^ sw) >> 1;
        s16x8 pf = *(const s16x8*)&Pw[c * DK + co];
#pragma unroll
        for (int d = 0; d < 4; ++d)
          oacc[d] = __builtin_amdgcn_mfma_f32_16x16x32_bf16(pf, vf[ks][d], oacc[d], 0, 0, 0);
      }
    };

    s16x8 kA[4][2], kB[4][2];
    loadk(kA, 0);
    for (int t = 0; t < ntw; t += 2) {
      step(kA, kB, t);
      if (t + 1 < ntw) step(kB, kA, t + 1);
    }

    // ---- normalize + store bf16 [B,N,H*64]; O rows are q = wq0+g*4+r
    float lT[4];
#pragma unroll
    for (int r = 0; r < 4; ++r) lT[r] = __shfl(lr, (g << 2) + r);
#pragma unroll
    for (int r = 0; r < 4; ++r) {
      float inv = lT[r] > 0.f ? 1.f / lT[r] : 0.f;
#pragma unroll
      for (int d = 0; d < 4; ++d) {
        size_t idx = (size_t)(b * N_ + wq0 + g * 4 + r) * D_MODEL + h * DK + d * 16 + c;
        Out[idx] = f2b(oacc[d][r] * inv);
      }
    }
  }
}

extern "C" void kernel_launch(void* const* d_in, const int* in_sizes, int n_in,
                              void* d_out, int out_size, void* d_ws, size_t ws_size,
                              hipStream_t stream) {
  const float* q = (const float*)d_in[0];
  const float* k = (const float*)d_in[1];
  const float* v = (const float*)d_in[2];
  const int* mask = (const int*)d_in[3];
  const float* Wq = (const float*)d_in[4];
  const float* Wk = (const float*)d_in[5];
  const float* Wv = (const float*)d_in[6];
  const float* Wo = (const float*)d_in[7];
  float* out = (float*)d_out;

  char* ws = (char*)d_ws;
  const size_t SZ = (size_t)M_TOT * D_MODEL * 2; // 16 MiB per bf16 [8192,1024]
  u16* qb = (u16*)ws;
  u16* kb = (u16*)(ws + SZ);
  u16* vb = (u16*)(ws + 2 * SZ);
  u16* Qp = (u16*)(ws + 3 * SZ);
  u16* Kp = (u16*)(ws + 4 * SZ);
  u16* Wqt = (u16*)(ws + 5 * SZ);
  u16* Wkt = Wqt + 1024 * 1024;
  u16* Wvt = Wkt + 1024 * 1024;
  u16* Wot = Wvt + 1024 * 1024;
  float* Mb = (float*)(Wot + 1024 * 1024);
  // aliases (lifetime-disjoint):
  u16* attn_out = qb; // qb dead after Q GEMM
  u16* Vp = kb;       // kb dead after K GEMM
  u16* Vt = vb;       // vb dead after V GEMM

  int n4 = M_TOT * D_MODEL / 4;
  cvt_f32_bf16<<<n4 / 256, 256, 0, stream>>>(q, qb, n4);
  cvt_f32_bf16<<<n4 / 256, 256, 0, stream>>>(k, kb, n4);
  cvt_f32_bf16<<<n4 / 256, 256, 0, stream>>>(v, vb, n4);
  mask_bias<<<(B_ * N_ + 255) / 256, 256, 0, stream>>>(mask, Mb, B_ * N_);
  dim3 wg(32, 32);
  wtrans<<<wg, 256, 0, stream>>>(Wq, Wqt);
  wtrans<<<wg, 256, 0, stream>>>(Wk, Wkt);
  wtrans<<<wg, 256, 0, stream>>>(Wv, Wvt);
  wtrans<<<wg, 256, 0, stream>>>(Wo, Wot);
  dim3 gg(D_MODEL / 128, M_TOT / 128);
  gemm_bt<false><<<gg, 256, 0, stream>>>(qb, Wqt, nullptr, Qp, M_TOT, D_MODEL, D_MODEL);
  gemm_bt<false><<<gg, 256, 0, stream>>>(kb, Wkt, nullptr, Kp, M_TOT, D_MODEL, D_MODEL);
  gemm_bt<false><<<gg, 256, 0, stream>>>(vb, Wvt, nullptr, Vp, M_TOT, D_MODEL, D_MODEL);
  vtrans<<<dim3(N_ / 64, NHEAD, B_), 256, 0, stream>>>(Vp, Vt);
  attn_fwd<<<1024, 256, 0, stream>>>(Qp, Kp, Vt, Mb, attn_out);
  gemm_bt<true><<<gg, 256, 0, stream>>>(attn_out, Wot, out, nullptr, M_TOT, D_MODEL, D_MODEL);
}

// Round 9
// 349.592 us; speedup vs baseline: 1.2117x; 1.2117x over previous
//
#include <hip/hip_runtime.h>
#include <hip/hip_bf16.h>

typedef unsigned short u16;
typedef unsigned int u32;
typedef short s16x8 __attribute__((ext_vector_type(8)));
typedef float f32x4 __attribute__((ext_vector_type(4)));
typedef u16 u16x4 __attribute__((ext_vector_type(4)));
typedef u16 u16x8 __attribute__((ext_vector_type(8)));
typedef u32 u32x2 __attribute__((ext_vector_type(2)));

#define D_MODEL 1024
#define NHEAD 16
#define DK 64
#define B_ 4
#define N_ 2048
#define M_TOT (B_ * N_) /* 8192 */
#define QBLK 128
#define KVBLK 64
#define SCALE2 0.1803368801111137f /* 0.125 * log2(e) */
#define MFIX 12.0f /* fixed softmax base (exact power-of-2 invariance) */

__device__ __forceinline__ u16 f2b(float x) {
  __hip_bfloat16 h = __float2bfloat16(x);
  return __builtin_bit_cast(u16, h);
}

__device__ __forceinline__ void gload_lds16(const void* gp, void* lp) {
  __builtin_amdgcn_global_load_lds(
      (const __attribute__((address_space(1))) unsigned int*)gp,
      (__attribute__((address_space(3))) unsigned int*)lp, 16, 0, 0);
}

// ---------------- padding mask -> float bias (-MFIX or -inf) --------------
__global__ __launch_bounds__(256) void mask_bias(const int* __restrict__ mask,
                                                 float* __restrict__ Mb, int n) {
  int i = blockIdx.x * 256 + threadIdx.x;
  if (i < n) Mb[i] = mask[i] ? -MFIX : -INFINITY;
}

// ---------------- W (f32, [K][N]) -> W^T (bf16, [N][K]) ----------------
__global__ __launch_bounds__(256) void wtrans(const float* __restrict__ W,
                                              u16* __restrict__ Wt) {
  __shared__ float tile[32][33];
  int bi = blockIdx.y, bj = blockIdx.x;
  int tx = threadIdx.x & 31, ty = threadIdx.x >> 5; // 32 x 8
#pragma unroll
  for (int r = 0; r < 4; ++r)
    tile[ty + r * 8][tx] = W[(size_t)(bi * 32 + ty + r * 8) * D_MODEL + bj * 32 + tx];
  __syncthreads();
#pragma unroll
  for (int r = 0; r < 4; ++r)
    Wt[(size_t)(bj * 32 + ty + r * 8) * D_MODEL + bi * 32 + tx] = f2b(tile[tx][ty + r * 8]);
}

// ------------- V [B,N,H*64] bf16 -> Vt [B,H,64,N] bf16 -------------
__global__ __launch_bounds__(256) void vtrans(const u16* __restrict__ Vp,
                                              u16* __restrict__ Vt) {
  __shared__ u16 tile[64][65];
  int n0 = blockIdx.x * 64, h = blockIdx.y, b = blockIdx.z;
  int tx = threadIdx.x & 63, ty = threadIdx.x >> 6;
  for (int r = ty; r < 64; r += 4)
    tile[r][tx] = Vp[(size_t)(b * N_ + n0 + r) * D_MODEL + h * DK + tx];
  __syncthreads();
  for (int r = ty; r < 64; r += 4)
    Vt[((size_t)(b * NHEAD + h) * DK + r) * N_ + n0 + tx] = tile[tx][r];
}

// ------------- GEMM: C[M,N] = A[M,K] * Bt[N,K]^T (bf16 MFMA) -------------
// AMODE 0: A bf16, staged via global_load_lds.
// AMODE 1: A f32, reg-staged with on-the-fly bf16 conversion (fused cvt).
template <int AMODE, bool OUT_F32>
__global__ __launch_bounds__(256) void gemm_bt(const u16* __restrict__ Ab,
                                               const float* __restrict__ Af,
                                               const u16* __restrict__ Bt,
                                               float* __restrict__ Cf,
                                               u16* __restrict__ Cb,
                                               int M, int N, int K) {
  __shared__ __align__(16) u16 Atile[128 * 32];
  __shared__ __align__(16) u16 Btile[128 * 32];
  int tid = threadIdx.x;
  int w = tid >> 6, lane = tid & 63;
  int g = lane >> 4, c = lane & 15;
  int wr = w >> 1, wc = w & 1;
  int bi = blockIdx.y, bj = blockIdx.x;
  const int rowA0 = bi * 128, rowB0 = bj * 128;

  const f32x4 fzero = {0.f, 0.f, 0.f, 0.f};
  f32x4 acc[4][4];
#pragma unroll
  for (int m = 0; m < 4; ++m)
#pragma unroll
    for (int n = 0; n < 4; ++n) acc[m][n] = fzero;

  for (int k0 = 0; k0 < K; k0 += 32) {
#pragma unroll
    for (int cc = 0; cc < 2; ++cc) {
      int li = w * 2 + cc;
      if (AMODE == 0) {
        const u16* ga = Ab + (size_t)(rowA0 + li * 16 + (lane >> 2)) * K + k0 + (lane & 3) * 8;
        gload_lds16(ga, &Atile[li * 512]);
      } else {
        int row = lane >> 2, colf = (lane & 3) * 8;
        const float* gaf = Af + (size_t)(rowA0 + li * 16 + row) * K + k0 + colf;
        f32x4 v0 = *(const f32x4*)gaf;
        f32x4 v1 = *(const f32x4*)(gaf + 4);
        u16x8 o;
        o[0] = f2b(v0[0]); o[1] = f2b(v0[1]); o[2] = f2b(v0[2]); o[3] = f2b(v0[3]);
        o[4] = f2b(v1[0]); o[5] = f2b(v1[1]); o[6] = f2b(v1[2]); o[7] = f2b(v1[3]);
        *(u16x8*)&Atile[li * 512 + row * 32 + colf] = o;
      }
      const u16* gb = Bt + (size_t)(rowB0 + li * 16 + (lane >> 2)) * K + k0 + (lane & 3) * 8;
      gload_lds16(gb, &Btile[li * 512]);
    }
    __syncthreads();
    s16x8 af[4], bfr[4];
#pragma unroll
    for (int m = 0; m < 4; ++m)
      af[m] = *(const s16x8*)&Atile[(wr * 64 + m * 16 + c) * 32 + g * 8];
#pragma unroll
    for (int n = 0; n < 4; ++n)
      bfr[n] = *(const s16x8*)&Btile[(wc * 64 + n * 16 + c) * 32 + g * 8];
#pragma unroll
    for (int m = 0; m < 4; ++m)
#pragma unroll
      for (int n = 0; n < 4; ++n)
        acc[m][n] = __builtin_amdgcn_mfma_f32_16x16x32_bf16(af[m], bfr[n], acc[m][n], 0, 0, 0);
    __syncthreads();
  }
#pragma unroll
  for (int m = 0; m < 4; ++m)
#pragma unroll
    for (int n = 0; n < 4; ++n)
#pragma unroll
      for (int r = 0; r < 4; ++r) {
        int row = rowA0 + wr * 64 + m * 16 + g * 4 + r;
        int col = rowB0 + wc * 64 + n * 16 + c;
        size_t idx = (size_t)row * N + col;
        if (OUT_F32) Cf[idx] = acc[m][n][r];
        else Cb[idx] = f2b(acc[m][n][r]);
      }
}

// ------------- causal flash attention, swapped QK^T, pipelined ------------
// R7 structure (best measured): XCD-local heads, paired q-tiles {15-p,p},
// K reg double-buffer prefetch, V at tile top, no __syncthreads.
// NEW: fixed softmax base (no max tracking) -> feed-forward per-tile chain.
__global__ __launch_bounds__(256) void attn_fwd(const u16* __restrict__ Qp,
                                                const u16* __restrict__ Kp,
                                                const u16* __restrict__ Vt,
                                                const float* __restrict__ Mb,
                                                u16* __restrict__ Out) {
  __shared__ __align__(16) u16 Plds[4][32 * KVBLK];
  // 512 blocks: xcd = bid&7 owns heads [xcd*8, xcd*8+8); pair p -> {15-p, p}
  int bid = blockIdx.x;
  int xcd = bid & 7;
  int inner = bid >> 3; // 0..63
  int j = inner >> 3;   // head-within-XCD 0..7
  int pair = inner & 7; // 0..7
  int bh = xcd * 8 + j; // 0..63
  int b = bh >> 4, h = bh & 15;
  int tid = threadIdx.x, w = tid >> 6, lane = tid & 63;
  int g = lane >> 4, c = lane & 15;

  const u16* kbase = Kp + (size_t)b * N_ * D_MODEL + h * DK;
  const u16* vbase = Vt + (size_t)(b * NHEAD + h) * DK * N_;
  const float* mp0 = Mb + (size_t)b * N_;

  const f32x4 fzero = {0.f, 0.f, 0.f, 0.f};
  int sw = (c & 7) << 4;
  u16* Pw = &Plds[w][0];

#pragma unroll 1
  for (int ph = 0; ph < 2; ++ph) {
    int qt = ph ? pair : 15 - pair;
    int q0 = qt * QBLK;
    int wq0 = q0 + w * 32; // this wave's first q row
    int ntw = wq0 / KVBLK + 1;

    // Q fragments (B-operand): lane holds Q[wq0+m*16+c][kh*32+g*8+e]
    s16x8 qf[2][2];
#pragma unroll
    for (int m = 0; m < 2; ++m) {
      const u16* qb2 = Qp + (size_t)(b * N_ + wq0 + m * 16 + c) * D_MODEL + h * DK;
#pragma unroll
      for (int kh = 0; kh < 2; ++kh) qf[m][kh] = *(const s16x8*)(qb2 + kh * 32 + g * 8);
    }

    f32x4 oacc[2][4];
#pragma unroll
    for (int m = 0; m < 2; ++m)
#pragma unroll
      for (int d = 0; d < 4; ++d) oacc[m][d] = fzero;
    float lr[2] = {0.f, 0.f};

    auto loadk = [&](s16x8(&kf)[4][2], int t) {
      int kv0 = t * KVBLK;
#pragma unroll
      for (int n = 0; n < 4; ++n) {
        const u16* kr = &kbase[(size_t)(kv0 + n * 16 + c) * D_MODEL + g * 8];
        kf[n][0] = *(const s16x8*)kr;
        kf[n][1] = *(const s16x8*)(kr + 32);
      }
    };

    auto step = [&](s16x8(&kc)[4][2], s16x8(&kn)[4][2], int t) {
      int kv0 = t * KVBLK;
      // prefetch next K tile into the other reg bank (hidden by this tile)
      if (t + 1 < ntw) loadk(kn, t + 1);
      // V fragments for THIS tile issued up front (consumed late)
      s16x8 vf[2][4];
#pragma unroll
      for (int ks = 0; ks < 2; ++ks)
#pragma unroll
        for (int d = 0; d < 4; ++d)
          vf[ks][d] = *(const s16x8*)&vbase[(size_t)(d * 16 + c) * N_ + kv0 + ks * 32 + g * 8];
      f32x4 mbv[4];
#pragma unroll
      for (int n = 0; n < 4; ++n) mbv[n] = *(const f32x4*)&mp0[kv0 + n * 16 + g * 4];

      // ---- S^T = K Q^T : st[m][n][r] = S[q=wq0+m*16+c][kv=kv0+n*16+g*4+r]
      f32x4 st[2][4];
#pragma unroll
      for (int n = 0; n < 4; ++n)
#pragma unroll
        for (int m = 0; m < 2; ++m) {
          f32x4 acc = __builtin_amdgcn_mfma_f32_16x16x32_bf16(kc[n][0], qf[m][0], fzero, 0, 0, 0);
          st[m][n] = __builtin_amdgcn_mfma_f32_16x16x32_bf16(kc[n][1], qf[m][1], acc, 0, 0, 0);
        }

      // ---- p = exp2(s*SCALE2 + bias - MFIX), causal mask; no max tracking
      bool diag = (kv0 + KVBLK - 1 > wq0);
#pragma unroll
      for (int m = 0; m < 2; ++m) {
        float rs = 0.f;
        int qq = wq0 + m * 16 + c;
#pragma unroll
        for (int n = 0; n < 4; ++n) {
#pragma unroll
          for (int r = 0; r < 4; ++r) {
            float v = fmaf(st[m][n][r], SCALE2, mbv[n][r]);
            if (diag) {
              int kv = kv0 + n * 16 + g * 4 + r;
              v = (kv > qq) ? -INFINITY : v;
            }
            float p = exp2f(v);
            st[m][n][r] = p;
            rs += p;
          }
          u32 lo = (u32)f2b(st[m][n][0]) | ((u32)f2b(st[m][n][1]) << 16);
          u32 hi = (u32)f2b(st[m][n][2]) | ((u32)f2b(st[m][n][3]) << 16);
          u32x2 pv = {lo, hi};
          *(u32x2*)&Pw[(m * 16 + c) * DK + (((n * 32 + g * 8) ^ sw) >> 1)] = pv;
        }
        rs += __shfl_xor(rs, 16);
        rs += __shfl_xor(rs, 32);
        lr[m] += rs;
      }

      // ---- O += P * V
#pragma unroll
      for (int ks = 0; ks < 2; ++ks) {
        int co = ((ks * 64 + g * 16) ^ sw) >> 1;
        s16x8 pf[2];
#pragma unroll
        for (int m = 0; m < 2; ++m)
          pf[m] = *(const s16x8*)&Pw[(m * 16 + c) * DK + co];
#pragma unroll
        for (int d = 0; d < 4; ++d)
#pragma unroll
          for (int m = 0; m < 2; ++m)
            oacc[m][d] = __builtin_amdgcn_mfma_f32_16x16x32_bf16(pf[m], vf[ks][d], oacc[m][d], 0, 0, 0);
      }
    };

    s16x8 kA[4][2], kB[4][2];
    loadk(kA, 0);
    for (int t = 0; t < ntw; t += 2) {
      step(kA, kB, t);
      if (t + 1 < ntw) step(kB, kA, t + 1);
    }

    // ---- normalize + store bf16 [B,N,H*64]; O rows are q = wq0+m*16+g*4+r
#pragma unroll
    for (int m = 0; m < 2; ++m) {
      float lT[4];
#pragma unroll
      for (int r = 0; r < 4; ++r) lT[r] = __shfl(lr[m], (g << 2) + r);
#pragma unroll
      for (int r = 0; r < 4; ++r) {
        float inv = lT[r] > 0.f ? 1.f / lT[r] : 0.f;
#pragma unroll
        for (int d = 0; d < 4; ++d) {
          size_t idx = (size_t)(b * N_ + wq0 + m * 16 + g * 4 + r) * D_MODEL + h * DK + d * 16 + c;
          Out[idx] = f2b(oacc[m][d][r] * inv);
        }
      }
    }
  }
}

extern "C" void kernel_launch(void* const* d_in, const int* in_sizes, int n_in,
                              void* d_out, int out_size, void* d_ws, size_t ws_size,
                              hipStream_t stream) {
  const float* q = (const float*)d_in[0];
  const float* k = (const float*)d_in[1];
  const float* v = (const float*)d_in[2];
  const int* mask = (const int*)d_in[3];
  const float* Wq = (const float*)d_in[4];
  const float* Wk = (const float*)d_in[5];
  const float* Wv = (const float*)d_in[6];
  const float* Wo = (const float*)d_in[7];
  float* out = (float*)d_out;

  char* ws = (char*)d_ws;
  const size_t SZ = (size_t)M_TOT * D_MODEL * 2; // 16 MiB per bf16 [8192,1024]
  u16* attn_out = (u16*)ws;
  u16* Qp = (u16*)(ws + 1 * SZ);
  u16* Kp = (u16*)(ws + 2 * SZ);
  u16* Vp = (u16*)(ws + 3 * SZ);
  u16* Vt = (u16*)(ws + 4 * SZ);
  u16* Wqt = (u16*)(ws + 5 * SZ);
  u16* Wkt = Wqt + 1024 * 1024;
  u16* Wvt = Wkt + 1024 * 1024;
  u16* Wot = Wvt + 1024 * 1024;
  float* Mb = (float*)(Wot + 1024 * 1024);

  mask_bias<<<(B_ * N_ + 255) / 256, 256, 0, stream>>>(mask, Mb, B_ * N_);
  dim3 wg(32, 32);
  wtrans<<<wg, 256, 0, stream>>>(Wq, Wqt);
  wtrans<<<wg, 256, 0, stream>>>(Wk, Wkt);
  wtrans<<<wg, 256, 0, stream>>>(Wv, Wvt);
  wtrans<<<wg, 256, 0, stream>>>(Wo, Wot);
  dim3 gg(D_MODEL / 128, M_TOT / 128);
  // fused f32->bf16 projections (A reg-staged with conversion)
  gemm_bt<1, false><<<gg, 256, 0, stream>>>(nullptr, q, Wqt, nullptr, Qp, M_TOT, D_MODEL, D_MODEL);
  gemm_bt<1, false><<<gg, 256, 0, stream>>>(nullptr, k, Wkt, nullptr, Kp, M_TOT, D_MODEL, D_MODEL);
  gemm_bt<1, false><<<gg, 256, 0, stream>>>(nullptr, v, Wvt, nullptr, Vp, M_TOT, D_MODEL, D_MODEL);
  vtrans<<<dim3(N_ / 64, NHEAD, B_), 256, 0, stream>>>(Vp, Vt);
  attn_fwd<<<512, 256, 0, stream>>>(Qp, Kp, Vt, Mb, attn_out);
  gemm_bt<0, true><<<gg, 256, 0, stream>>>(attn_out, nullptr, Wot, out, nullptr, M_TOT, D_MODEL, D_MODEL);
}

// Round 10
// 348.742 us; speedup vs baseline: 1.2146x; 1.0024x over previous
//
#include <hip/hip_runtime.h>
#include <hip/hip_bf16.h>

typedef unsigned short u16;
typedef unsigned int u32;
typedef short s16x8 __attribute__((ext_vector_type(8)));
typedef float f32x4 __attribute__((ext_vector_type(4)));
typedef u16 u16x4 __attribute__((ext_vector_type(4)));
typedef u32 u32x2 __attribute__((ext_vector_type(2)));

#define D_MODEL 1024
#define NHEAD 16
#define DK 64
#define B_ 4
#define N_ 2048
#define M_TOT (B_ * N_) /* 8192 */
#define QBLK 128
#define KVBLK 64
#define SCALE2 0.1803368801111137f /* 0.125 * log2(e) */

__device__ __forceinline__ u16 f2b(float x) {
  __hip_bfloat16 h = __float2bfloat16(x);
  return __builtin_bit_cast(u16, h);
}

__device__ __forceinline__ void gload_lds16(const void* gp, void* lp) {
  __builtin_amdgcn_global_load_lds(
      (const __attribute__((address_space(1))) unsigned int*)gp,
      (__attribute__((address_space(3))) unsigned int*)lp, 16, 0, 0);
}

// ---------------- elementwise f32 -> bf16 ----------------
__global__ __launch_bounds__(256) void cvt_f32_bf16(const float* __restrict__ x,
                                                    u16* __restrict__ y, int n4) {
  int i = blockIdx.x * 256 + threadIdx.x;
  if (i < n4) {
    f32x4 v = *(const f32x4*)(x + (size_t)i * 4);
    u16x4 o;
    o[0] = f2b(v[0]); o[1] = f2b(v[1]); o[2] = f2b(v[2]); o[3] = f2b(v[3]);
    *(u16x4*)(y + (size_t)i * 4) = o;
  }
}

// ---------------- padding mask -> float bias (0 or -inf) ----------------
__global__ __launch_bounds__(256) void mask_bias(const int* __restrict__ mask,
                                                 float* __restrict__ Mb, int n) {
  int i = blockIdx.x * 256 + threadIdx.x;
  if (i < n) Mb[i] = mask[i] ? 0.f : -INFINITY;
}

// ---------------- W (f32, [K][N]) -> W^T (bf16, [N][K]) ----------------
__global__ __launch_bounds__(256) void wtrans(const float* __restrict__ W,
                                              u16* __restrict__ Wt) {
  __shared__ float tile[32][33];
  int bi = blockIdx.y, bj = blockIdx.x;
  int tx = threadIdx.x & 31, ty = threadIdx.x >> 5; // 32 x 8
#pragma unroll
  for (int r = 0; r < 4; ++r)
    tile[ty + r * 8][tx] = W[(size_t)(bi * 32 + ty + r * 8) * D_MODEL + bj * 32 + tx];
  __syncthreads();
#pragma unroll
  for (int r = 0; r < 4; ++r)
    Wt[(size_t)(bj * 32 + ty + r * 8) * D_MODEL + bi * 32 + tx] = f2b(tile[tx][ty + r * 8]);
}

// ------------- V [B,N,H*64] bf16 -> Vt [B,H,64,N] bf16 -------------
__global__ __launch_bounds__(256) void vtrans(const u16* __restrict__ Vp,
                                              u16* __restrict__ Vt) {
  __shared__ u16 tile[64][65];
  int n0 = blockIdx.x * 64, h = blockIdx.y, b = blockIdx.z;
  int tx = threadIdx.x & 63, ty = threadIdx.x >> 6;
  for (int r = ty; r < 64; r += 4)
    tile[r][tx] = Vp[(size_t)(b * N_ + n0 + r) * D_MODEL + h * DK + tx];
  __syncthreads();
  for (int r = ty; r < 64; r += 4)
    Vt[((size_t)(b * NHEAD + h) * DK + r) * N_ + n0 + tx] = tile[tx][r];
}

// ------------- GEMM: C[M,N] = A[M,K](bf16) * Bt[N,K](bf16)^T -------------
template <bool OUT_F32>
__global__ __launch_bounds__(256) void gemm_bt(const u16* __restrict__ A,
                                               const u16* __restrict__ Bt,
                                               float* __restrict__ Cf,
                                               u16* __restrict__ Cb,
                                               int M, int N, int K) {
  __shared__ __align__(16) u16 Atile[128 * 32];
  __shared__ __align__(16) u16 Btile[128 * 32];
  int tid = threadIdx.x;
  int w = tid >> 6, lane = tid & 63;
  int g = lane >> 4, c = lane & 15;
  int wr = w >> 1, wc = w & 1;
  int bi = blockIdx.y, bj = blockIdx.x;
  const int rowA0 = bi * 128, rowB0 = bj * 128;

  const f32x4 fzero = {0.f, 0.f, 0.f, 0.f};
  f32x4 acc[4][4];
#pragma unroll
  for (int m = 0; m < 4; ++m)
#pragma unroll
    for (int n = 0; n < 4; ++n) acc[m][n] = fzero;

  for (int k0 = 0; k0 < K; k0 += 32) {
#pragma unroll
    for (int cc = 0; cc < 2; ++cc) {
      int li = w * 2 + cc;
      const u16* ga = A + (size_t)(rowA0 + li * 16 + (lane >> 2)) * K + k0 + (lane & 3) * 8;
      gload_lds16(ga, &Atile[li * 512]);
      const u16* gb = Bt + (size_t)(rowB0 + li * 16 + (lane >> 2)) * K + k0 + (lane & 3) * 8;
      gload_lds16(gb, &Btile[li * 512]);
    }
    __syncthreads();
    s16x8 af[4], bfr[4];
#pragma unroll
    for (int m = 0; m < 4; ++m)
      af[m] = *(const s16x8*)&Atile[(wr * 64 + m * 16 + c) * 32 + g * 8];
#pragma unroll
    for (int n = 0; n < 4; ++n)
      bfr[n] = *(const s16x8*)&Btile[(wc * 64 + n * 16 + c) * 32 + g * 8];
#pragma unroll
    for (int m = 0; m < 4; ++m)
#pragma unroll
      for (int n = 0; n < 4; ++n)
        acc[m][n] = __builtin_amdgcn_mfma_f32_16x16x32_bf16(af[m], bfr[n], acc[m][n], 0, 0, 0);
    __syncthreads();
  }
#pragma unroll
  for (int m = 0; m < 4; ++m)
#pragma unroll
    for (int n = 0; n < 4; ++n)
#pragma unroll
      for (int r = 0; r < 4; ++r) {
        int row = rowA0 + wr * 64 + m * 16 + g * 4 + r;
        int col = rowB0 + wc * 64 + n * 16 + c;
        size_t idx = (size_t)row * N + col;
        if (OUT_F32) Cf[idx] = acc[m][n][r];
        else Cb[idx] = f2b(acc[m][n][r]);
      }
}

// ------------- causal flash attention: LDS-staged K/V + XCD-local ---------
// Block-shared K/V staging (coalesced global_load_lds, XOR-swizzled via
// pre-swizzled source), double-buffered with counted vmcnt(4). XCD-local
// heads, paired q-tiles {15-p, p}, defer-max softmax, swapped QK^T.
__global__ __launch_bounds__(256) void attn_fwd(const u16* __restrict__ Qp,
                                                const u16* __restrict__ Kp,
                                                const u16* __restrict__ Vt,
                                                const float* __restrict__ Mb,
                                                u16* __restrict__ Out) {
  __shared__ __align__(16) u16 Klds[2][KVBLK * DK];
  __shared__ __align__(16) u16 Vlds[2][DK * KVBLK];
  __shared__ __align__(16) u16 Plds[4][32 * DK];
  // 512 blocks: xcd = bid&7 owns heads [xcd*8, xcd*8+8); pair p -> {15-p, p}
  int bid = blockIdx.x;
  int xcd = bid & 7;
  int inner = bid >> 3; // 0..63
  int j = inner >> 3;   // head-within-XCD 0..7
  int pair = inner & 7; // 0..7
  int bh = xcd * 8 + j; // 0..63
  int b = bh >> 4, h = bh & 15;
  int tid = threadIdx.x, w = tid >> 6, lane = tid & 63;
  int g = lane >> 4, c = lane & 15;

  const u16* kbase = Kp + (size_t)b * N_ * D_MODEL + h * DK;
  const u16* vbase = Vt + (size_t)(b * NHEAD + h) * DK * N_;
  const float* mp0 = Mb + (size_t)b * N_;

  const f32x4 fzero = {0.f, 0.f, 0.f, 0.f};
  int sw = (c & 7) << 4;
  u16* Pw = &Plds[w][0];

  // staging geometry: 8 rows/instr, 8 lanes/row; pre-swizzled source col
  int srow = lane >> 3;                         // 0..7
  int scol = (((lane & 7) * 16) ^ (srow << 4)) >> 1; // elems
  int r0 = w * 16, r1 = w * 16 + 8;

#pragma unroll 1
  for (int ph = 0; ph < 2; ++ph) {
    int qt = ph ? pair : 15 - pair;
    int q0 = qt * QBLK;
    int wq0 = q0 + w * 32; // this wave's first q row
    int nt = 2 * qt + 2;   // block-uniform tile count

    // Q fragments (B-operand): lane holds Q[wq0+m*16+c][kh*32+g*8+e]
    s16x8 qf[2][2];
#pragma unroll
    for (int m = 0; m < 2; ++m) {
      const u16* qb2 = Qp + (size_t)(b * N_ + wq0 + m * 16 + c) * D_MODEL + h * DK;
#pragma unroll
      for (int kh = 0; kh < 2; ++kh) qf[m][kh] = *(const s16x8*)(qb2 + kh * 32 + g * 8);
    }

    f32x4 oacc[2][4];
#pragma unroll
    for (int m = 0; m < 2; ++m)
#pragma unroll
      for (int d = 0; d < 4; ++d) oacc[m][d] = fzero;
    float mr[2] = {-1e30f, -1e30f}, lr[2] = {0.f, 0.f};

    auto stage = [&](int t, int bn) {
      int kv0 = t * KVBLK;
      gload_lds16(kbase + (size_t)(kv0 + r0 + srow) * D_MODEL + scol, &Klds[bn][r0 * DK]);
      gload_lds16(kbase + (size_t)(kv0 + r1 + srow) * D_MODEL + scol, &Klds[bn][r1 * DK]);
      gload_lds16(vbase + (size_t)(r0 + srow) * N_ + kv0 + scol, &Vlds[bn][r0 * DK]);
      gload_lds16(vbase + (size_t)(r1 + srow) * N_ + kv0 + scol, &Vlds[bn][r1 * DK]);
    };

    stage(0, 0); // prologue
    for (int t = 0; t < nt; ++t) {
      int kv0 = t * KVBLK;
      bool active = (kv0 <= wq0 + 31);
      f32x4 mbv[4];
      if (active) {
#pragma unroll
        for (int n = 0; n < 4; ++n)
          mbv[n] = *(const f32x4*)&mp0[kv0 + n * 16 + g * 4];
      }
      if (t + 1 < nt) {
        stage(t + 1, (t + 1) & 1);
        asm volatile("s_waitcnt vmcnt(4)" ::: "memory");
      } else {
        asm volatile("s_waitcnt vmcnt(0)" ::: "memory");
      }
      __syncthreads();

      if (active) {
        const u16* Kl = Klds[t & 1];
        const u16* Vl = Vlds[t & 1];

        // ---- S^T = K Q^T : st[m][n][r] = S[q=wq0+m*16+c][kv=kv0+n*16+g*4+r]
        f32x4 st[2][4];
#pragma unroll
        for (int n = 0; n < 4; ++n) {
          const u16* kr = &Kl[(n * 16 + c) * DK];
          s16x8 kf0 = *(const s16x8*)&kr[((g * 16) ^ sw) >> 1];
          s16x8 kf1 = *(const s16x8*)&kr[((g * 16 + 64) ^ sw) >> 1];
#pragma unroll
          for (int m = 0; m < 2; ++m) {
            f32x4 acc = __builtin_amdgcn_mfma_f32_16x16x32_bf16(kf0, qf[m][0], fzero, 0, 0, 0);
            st[m][n] = __builtin_amdgcn_mfma_f32_16x16x32_bf16(kf1, qf[m][1], acc, 0, 0, 0);
          }
        }

        // ---- scale + padding bias + causal mask, per-lane row max
        bool diag = (kv0 + KVBLK - 1 > wq0);
        float pmax[2];
#pragma unroll
        for (int m = 0; m < 2; ++m) {
          int qq = wq0 + m * 16 + c;
#pragma unroll
          for (int n = 0; n < 4; ++n)
#pragma unroll
            for (int r = 0; r < 4; ++r) {
              float v = fmaf(st[m][n][r], SCALE2, mbv[n][r]);
              if (diag) {
                int kv = kv0 + n * 16 + g * 4 + r;
                v = (kv > qq) ? -INFINITY : v;
              }
              st[m][n][r] = v;
            }
          float m01 = fmaxf(fmaxf(st[m][0][0], st[m][0][1]), fmaxf(st[m][0][2], st[m][0][3]));
          float m11 = fmaxf(fmaxf(st[m][1][0], st[m][1][1]), fmaxf(st[m][1][2], st[m][1][3]));
          float m21 = fmaxf(fmaxf(st[m][2][0], st[m][2][1]), fmaxf(st[m][2][2], st[m][2][3]));
          float m31 = fmaxf(fmaxf(st[m][3][0], st[m][3][1]), fmaxf(st[m][3][2], st[m][3][3]));
          float pm = fmaxf(fmaxf(m01, m11), fmaxf(m21, m31));
          pm = fmaxf(pm, __shfl_xor(pm, 16));
          pm = fmaxf(pm, __shfl_xor(pm, 32));
          pmax[m] = pm;
        }

        // ---- defer-max rescale (T13)
#pragma unroll
        for (int m = 0; m < 2; ++m) {
          if (__any(pmax[m] > mr[m] + 8.f)) {
            float mnew = fmaxf(mr[m], pmax[m]);
            float al = exp2f(mr[m] - mnew);
            mr[m] = mnew;
            lr[m] *= al;
            float alT[4];
#pragma unroll
            for (int r = 0; r < 4; ++r) alT[r] = __shfl(al, (g << 2) + r);
#pragma unroll
            for (int d = 0; d < 4; ++d)
#pragma unroll
              for (int r = 0; r < 4; ++r) oacc[m][d][r] *= alT[r];
          }
        }

        // ---- p = exp2(s - m), row sum, P -> wave-private LDS (swizzled)
#pragma unroll
        for (int m = 0; m < 2; ++m) {
          float rs = 0.f;
#pragma unroll
          for (int n = 0; n < 4; ++n) {
#pragma unroll
            for (int r = 0; r < 4; ++r) {
              float p = exp2f(st[m][n][r] - mr[m]);
              st[m][n][r] = p;
              rs += p;
            }
            u32 lo = (u32)f2b(st[m][n][0]) | ((u32)f2b(st[m][n][1]) << 16);
            u32 hi = (u32)f2b(st[m][n][2]) | ((u32)f2b(st[m][n][3]) << 16);
            u32x2 pv = {lo, hi};
            *(u32x2*)&Pw[(m * 16 + c) * DK + (((n * 32 + g * 8) ^ sw) >> 1)] = pv;
          }
          rs += __shfl_xor(rs, 16);
          rs += __shfl_xor(rs, 32);
          lr[m] += rs;
        }

        // ---- O += P * V
#pragma unroll
        for (int ks = 0; ks < 2; ++ks) {
          int co = ((ks * 64 + g * 16) ^ sw) >> 1;
          s16x8 pf[2];
#pragma unroll
          for (int m = 0; m < 2; ++m)
            pf[m] = *(const s16x8*)&Pw[(m * 16 + c) * DK + co];
#pragma unroll
          for (int d = 0; d < 4; ++d) {
            s16x8 vf = *(const s16x8*)&Vl[(d * 16 + c) * DK + co];
#pragma unroll
            for (int m = 0; m < 2; ++m)
              oacc[m][d] = __builtin_amdgcn_mfma_f32_16x16x32_bf16(pf[m], vf, oacc[m][d], 0, 0, 0);
          }
        }
      }
      __syncthreads();
    }

    // ---- normalize + store bf16 [B,N,H*64]; O rows are q = wq0+m*16+g*4+r
#pragma unroll
    for (int m = 0; m < 2; ++m) {
      float lT[4];
#pragma unroll
      for (int r = 0; r < 4; ++r) lT[r] = __shfl(lr[m], (g << 2) + r);
#pragma unroll
      for (int r = 0; r < 4; ++r) {
        float inv = lT[r] > 0.f ? 1.f / lT[r] : 0.f;
#pragma unroll
        for (int d = 0; d < 4; ++d) {
          size_t idx = (size_t)(b * N_ + wq0 + m * 16 + g * 4 + r) * D_MODEL + h * DK + d * 16 + c;
          Out[idx] = f2b(oacc[m][d][r] * inv);
        }
      }
    }
  }
}

extern "C" void kernel_launch(void* const* d_in, const int* in_sizes, int n_in,
                              void* d_out, int out_size, void* d_ws, size_t ws_size,
                              hipStream_t stream) {
  const float* q = (const float*)d_in[0];
  const float* k = (const float*)d_in[1];
  const float* v = (const float*)d_in[2];
  const int* mask = (const int*)d_in[3];
  const float* Wq = (const float*)d_in[4];
  const float* Wk = (const float*)d_in[5];
  const float* Wv = (const float*)d_in[6];
  const float* Wo = (const float*)d_in[7];
  float* out = (float*)d_out;

  char* ws = (char*)d_ws;
  const size_t SZ = (size_t)M_TOT * D_MODEL * 2; // 16 MiB per bf16 [8192,1024]
  u16* qb = (u16*)ws;
  u16* kb = (u16*)(ws + SZ);
  u16* vb = (u16*)(ws + 2 * SZ);
  u16* Qp = (u16*)(ws + 3 * SZ);
  u16* Kp = (u16*)(ws + 4 * SZ);
  u16* Wqt = (u16*)(ws + 5 * SZ);
  u16* Wkt = Wqt + 1024 * 1024;
  u16* Wvt = Wkt + 1024 * 1024;
  u16* Wot = Wvt + 1024 * 1024;
  float* Mb = (float*)(Wot + 1024 * 1024);
  // aliases (lifetime-disjoint):
  u16* attn_out = qb; // qb dead after Q GEMM
  u16* Vp = kb;       // kb dead after K GEMM
  u16* Vt = vb;       // vb dead after V GEMM

  int n4 = M_TOT * D_MODEL / 4;
  cvt_f32_bf16<<<n4 / 256, 256, 0, stream>>>(q, qb, n4);
  cvt_f32_bf16<<<n4 / 256, 256, 0, stream>>>(k, kb, n4);
  cvt_f32_bf16<<<n4 / 256, 256, 0, stream>>>(v, vb, n4);
  mask_bias<<<(B_ * N_ + 255) / 256, 256, 0, stream>>>(mask, Mb, B_ * N_);
  dim3 wg(32, 32);
  wtrans<<<wg, 256, 0, stream>>>(Wq, Wqt);
  wtrans<<<wg, 256, 0, stream>>>(Wk, Wkt);
  wtrans<<<wg, 256, 0, stream>>>(Wv, Wvt);
  wtrans<<<wg, 256, 0, stream>>>(Wo, Wot);
  dim3 gg(D_MODEL / 128, M_TOT / 128);
  gemm_bt<false><<<gg, 256, 0, stream>>>(qb, Wqt, nullptr, Qp, M_TOT, D_MODEL, D_MODEL);
  gemm_bt<false><<<gg, 256, 0, stream>>>(kb, Wkt, nullptr, Kp, M_TOT, D_MODEL, D_MODEL);
  gemm_bt<false><<<gg, 256, 0, stream>>>(vb, Wvt, nullptr, Vp, M_TOT, D_MODEL, D_MODEL);
  vtrans<<<dim3(N_ / 64, NHEAD, B_), 256, 0, stream>>>(Vp, Vt);
  attn_fwd<<<512, 256, 0, stream>>>(Qp, Kp, Vt, Mb, attn_out);
  gemm_bt<true><<<gg, 256, 0, stream>>>(attn_out, Wot, out, nullptr, M_TOT, D_MODEL, D_MODEL);
}

// Round 11
// 328.994 us; speedup vs baseline: 1.2875x; 1.0600x over previous
//
#include <hip/hip_runtime.h>
#include <hip/hip_bf16.h>

typedef unsigned short u16;
typedef unsigned int u32;
typedef short s16x8 __attribute__((ext_vector_type(8)));
typedef float f32x4 __attribute__((ext_vector_type(4)));
typedef u16 u16x4 __attribute__((ext_vector_type(4)));
typedef u32 u32x2 __attribute__((ext_vector_type(2)));

#define D_MODEL 1024
#define NHEAD 16
#define DK 64
#define B_ 4
#define N_ 2048
#define M_TOT (B_ * N_) /* 8192 */
#define QBLK 128
#define KVBLK 64
#define SCALE2 0.1803368801111137f /* 0.125 * log2(e) */

__device__ __forceinline__ u16 f2b(float x) {
  __hip_bfloat16 h = __float2bfloat16(x);
  return __builtin_bit_cast(u16, h);
}

__device__ __forceinline__ void gload_lds16(const void* gp, void* lp) {
  __builtin_amdgcn_global_load_lds(
      (const __attribute__((address_space(1))) unsigned int*)gp,
      (__attribute__((address_space(3))) unsigned int*)lp, 16, 0, 0);
}

// ---------------- elementwise f32 -> bf16 ----------------
__global__ __launch_bounds__(256) void cvt_f32_bf16(const float* __restrict__ x,
                                                    u16* __restrict__ y, int n4) {
  int i = blockIdx.x * 256 + threadIdx.x;
  if (i < n4) {
    f32x4 v = *(const f32x4*)(x + (size_t)i * 4);
    u16x4 o;
    o[0] = f2b(v[0]); o[1] = f2b(v[1]); o[2] = f2b(v[2]); o[3] = f2b(v[3]);
    *(u16x4*)(y + (size_t)i * 4) = o;
  }
}

// ---------------- padding mask -> float bias (0 or -inf) ----------------
__global__ __launch_bounds__(256) void mask_bias(const int* __restrict__ mask,
                                                 float* __restrict__ Mb, int n) {
  int i = blockIdx.x * 256 + threadIdx.x;
  if (i < n) Mb[i] = mask[i] ? 0.f : -INFINITY;
}

// ---------------- W (f32, [K][N]) -> W^T (bf16, [N][K]) ----------------
__global__ __launch_bounds__(256) void wtrans(const float* __restrict__ W,
                                              u16* __restrict__ Wt) {
  __shared__ float tile[32][33];
  int bi = blockIdx.y, bj = blockIdx.x;
  int tx = threadIdx.x & 31, ty = threadIdx.x >> 5; // 32 x 8
#pragma unroll
  for (int r = 0; r < 4; ++r)
    tile[ty + r * 8][tx] = W[(size_t)(bi * 32 + ty + r * 8) * D_MODEL + bj * 32 + tx];
  __syncthreads();
#pragma unroll
  for (int r = 0; r < 4; ++r)
    Wt[(size_t)(bj * 32 + ty + r * 8) * D_MODEL + bi * 32 + tx] = f2b(tile[tx][ty + r * 8]);
}

// ------------- V [B,N,H*64] bf16 -> Vt [B,H,64,N] bf16 -------------
__global__ __launch_bounds__(256) void vtrans(const u16* __restrict__ Vp,
                                              u16* __restrict__ Vt) {
  __shared__ u16 tile[64][65];
  int n0 = blockIdx.x * 64, h = blockIdx.y, b = blockIdx.z;
  int tx = threadIdx.x & 63, ty = threadIdx.x >> 6;
  for (int r = ty; r < 64; r += 4)
    tile[r][tx] = Vp[(size_t)(b * N_ + n0 + r) * D_MODEL + h * DK + tx];
  __syncthreads();
  for (int r = ty; r < 64; r += 4)
    Vt[((size_t)(b * NHEAD + h) * DK + r) * N_ + n0 + tx] = tile[tx][r];
}

// ------------- GEMM: C[M,N] = A[M,K](bf16) * Bt[N,K](bf16)^T -------------
template <bool OUT_F32>
__global__ __launch_bounds__(256) void gemm_bt(const u16* __restrict__ A,
                                               const u16* __restrict__ Bt,
                                               float* __restrict__ Cf,
                                               u16* __restrict__ Cb,
                                               int M, int N, int K) {
  __shared__ __align__(16) u16 Atile[128 * 32];
  __shared__ __align__(16) u16 Btile[128 * 32];
  int tid = threadIdx.x;
  int w = tid >> 6, lane = tid & 63;
  int g = lane >> 4, c = lane & 15;
  int wr = w >> 1, wc = w & 1;
  int bi = blockIdx.y, bj = blockIdx.x;
  const int rowA0 = bi * 128, rowB0 = bj * 128;

  const f32x4 fzero = {0.f, 0.f, 0.f, 0.f};
  f32x4 acc[4][4];
#pragma unroll
  for (int m = 0; m < 4; ++m)
#pragma unroll
    for (int n = 0; n < 4; ++n) acc[m][n] = fzero;

  for (int k0 = 0; k0 < K; k0 += 32) {
#pragma unroll
    for (int cc = 0; cc < 2; ++cc) {
      int li = w * 2 + cc;
      const u16* ga = A + (size_t)(rowA0 + li * 16 + (lane >> 2)) * K + k0 + (lane & 3) * 8;
      gload_lds16(ga, &Atile[li * 512]);
      const u16* gb = Bt + (size_t)(rowB0 + li * 16 + (lane >> 2)) * K + k0 + (lane & 3) * 8;
      gload_lds16(gb, &Btile[li * 512]);
    }
    __syncthreads();
    s16x8 af[4], bfr[4];
#pragma unroll
    for (int m = 0; m < 4; ++m)
      af[m] = *(const s16x8*)&Atile[(wr * 64 + m * 16 + c) * 32 + g * 8];
#pragma unroll
    for (int n = 0; n < 4; ++n)
      bfr[n] = *(const s16x8*)&Btile[(wc * 64 + n * 16 + c) * 32 + g * 8];
#pragma unroll
    for (int m = 0; m < 4; ++m)
#pragma unroll
      for (int n = 0; n < 4; ++n)
        acc[m][n] = __builtin_amdgcn_mfma_f32_16x16x32_bf16(af[m], bfr[n], acc[m][n], 0, 0, 0);
    __syncthreads();
  }
#pragma unroll
  for (int m = 0; m < 4; ++m)
#pragma unroll
    for (int n = 0; n < 4; ++n)
#pragma unroll
      for (int r = 0; r < 4; ++r) {
        int row = rowA0 + wr * 64 + m * 16 + g * 4 + r;
        int col = rowB0 + wc * 64 + n * 16 + c;
        size_t idx = (size_t)row * N + col;
        if (OUT_F32) Cf[idx] = acc[m][n][r];
        else Cb[idx] = f2b(acc[m][n][r]);
      }
}

// ------------- causal flash attention, swapped QK^T, T15 pipeline ---------
// R7 base (XCD-local heads, paired q-tiles, K reg dbuf prefetch, reg-direct
// K/V, no __syncthreads) + cross-step pipeline: PV(t-1) runs inside iter t
// (P double-buffered in LDS), lazy softmax reductions (lane-local max +
// __any gate; l-sum deferred to epilogue).
__global__ __launch_bounds__(256) void attn_fwd(const u16* __restrict__ Qp,
                                                const u16* __restrict__ Kp,
                                                const u16* __restrict__ Vt,
                                                const float* __restrict__ Mb,
                                                u16* __restrict__ Out) {
  __shared__ __align__(16) u16 Plds[4][2][32 * DK]; // per-wave double-buffered P
  // 512 blocks: xcd = bid&7 owns heads [xcd*8, xcd*8+8); pair p -> {15-p, p}
  int bid = blockIdx.x;
  int xcd = bid & 7;
  int inner = bid >> 3; // 0..63
  int j = inner >> 3;   // head-within-XCD 0..7
  int pair = inner & 7; // 0..7
  int bh = xcd * 8 + j; // 0..63
  int b = bh >> 4, h = bh & 15;
  int tid = threadIdx.x, w = tid >> 6, lane = tid & 63;
  int g = lane >> 4, c = lane & 15;

  const u16* kbase = Kp + (size_t)b * N_ * D_MODEL + h * DK;
  const u16* vbase = Vt + (size_t)(b * NHEAD + h) * DK * N_;
  const float* mp0 = Mb + (size_t)b * N_;

  const f32x4 fzero = {0.f, 0.f, 0.f, 0.f};
  int sw = (c & 7) << 4;

#pragma unroll 1
  for (int ph = 0; ph < 2; ++ph) {
    int qt = ph ? pair : 15 - pair;
    int q0 = qt * QBLK;
    int wq0 = q0 + w * 32; // this wave's first q row
    int ntw = wq0 / KVBLK + 1;

    // Q fragments (B-operand): lane holds Q[wq0+m*16+c][kh*32+g*8+e]
    s16x8 qf[2][2];
#pragma unroll
    for (int m = 0; m < 2; ++m) {
      const u16* qb2 = Qp + (size_t)(b * N_ + wq0 + m * 16 + c) * D_MODEL + h * DK;
#pragma unroll
      for (int kh = 0; kh < 2; ++kh) qf[m][kh] = *(const s16x8*)(qb2 + kh * 32 + g * 8);
    }

    f32x4 oacc[2][4];
#pragma unroll
    for (int m = 0; m < 2; ++m)
#pragma unroll
      for (int d = 0; d < 4; ++d) oacc[m][d] = fzero;
    float mr[2] = {-1e30f, -1e30f}, lr[2] = {0.f, 0.f}; // lr = per-lane partial

    auto loadk = [&](s16x8(&kf)[4][2], int t) {
      int kv0 = t * KVBLK;
#pragma unroll
      for (int n = 0; n < 4; ++n) {
        const u16* kr = &kbase[(size_t)(kv0 + n * 16 + c) * D_MODEL + g * 8];
        kf[n][0] = *(const s16x8*)kr;
        kf[n][1] = *(const s16x8*)(kr + 32);
      }
    };
    auto loadv = [&](s16x8(&vf)[2][4], int t) {
      int kv0 = t * KVBLK;
#pragma unroll
      for (int ks = 0; ks < 2; ++ks)
#pragma unroll
        for (int d = 0; d < 4; ++d)
          vf[ks][d] = *(const s16x8*)&vbase[(size_t)(d * 16 + c) * N_ + kv0 + ks * 32 + g * 8];
    };
    auto loadmb = [&](f32x4(&mbv)[4], int t) {
      int kv0 = t * KVBLK;
#pragma unroll
      for (int n = 0; n < 4; ++n) mbv[n] = *(const f32x4*)&mp0[kv0 + n * 16 + g * 4];
    };
    auto qk = [&](s16x8(&kc)[4][2], f32x4(&st)[2][4]) {
#pragma unroll
      for (int n = 0; n < 4; ++n)
#pragma unroll
        for (int m = 0; m < 2; ++m) {
          f32x4 acc = __builtin_amdgcn_mfma_f32_16x16x32_bf16(kc[n][0], qf[m][0], fzero, 0, 0, 0);
          st[m][n] = __builtin_amdgcn_mfma_f32_16x16x32_bf16(kc[n][1], qf[m][1], acc, 0, 0, 0);
        }
    };
    auto pv = [&](int bufi, s16x8(&vf)[2][4]) {
      const u16* Pr = &Plds[w][bufi][0];
#pragma unroll
      for (int ks = 0; ks < 2; ++ks) {
        int co = ((ks * 64 + g * 16) ^ sw) >> 1;
        s16x8 pf[2];
#pragma unroll
        for (int m = 0; m < 2; ++m)
          pf[m] = *(const s16x8*)&Pr[(m * 16 + c) * DK + co];
#pragma unroll
        for (int d = 0; d < 4; ++d)
#pragma unroll
          for (int m = 0; m < 2; ++m)
            oacc[m][d] = __builtin_amdgcn_mfma_f32_16x16x32_bf16(pf[m], vf[ks][d], oacc[m][d], 0, 0, 0);
      }
    };
    auto smax = [&](int t, int bufi, f32x4(&st)[2][4], f32x4(&mbv)[4]) {
      int kv0 = t * KVBLK;
      bool diag = (kv0 + KVBLK - 1 > wq0);
      u16* Pwb = &Plds[w][bufi][0];
#pragma unroll
      for (int m = 0; m < 2; ++m) {
        int qq = wq0 + m * 16 + c;
#pragma unroll
        for (int n = 0; n < 4; ++n)
#pragma unroll
          for (int r = 0; r < 4; ++r) {
            float v = fmaf(st[m][n][r], SCALE2, mbv[n][r]);
            if (diag) {
              int kv = kv0 + n * 16 + g * 4 + r;
              v = (kv > qq) ? -INFINITY : v;
            }
            st[m][n][r] = v;
          }
        // lane-local max only; full reduce deferred to the (rare) rescale
        float a0 = fmaxf(fmaxf(st[m][0][0], st[m][0][1]), fmaxf(st[m][0][2], st[m][0][3]));
        float a1 = fmaxf(fmaxf(st[m][1][0], st[m][1][1]), fmaxf(st[m][1][2], st[m][1][3]));
        float a2 = fmaxf(fmaxf(st[m][2][0], st[m][2][1]), fmaxf(st[m][2][2], st[m][2][3]));
        float a3 = fmaxf(fmaxf(st[m][3][0], st[m][3][1]), fmaxf(st[m][3][2], st[m][3][3]));
        float pmL = fmaxf(fmaxf(a0, a1), fmaxf(a2, a3));
        if (__any(pmL > mr[m] + 8.f)) {
          float pm2 = fmaxf(pmL, __shfl_xor(pmL, 16));
          pm2 = fmaxf(pm2, __shfl_xor(pm2, 32));
          float mnew = fmaxf(mr[m], pm2);
          float al = exp2f(mr[m] - mnew); // wave-uniform
          mr[m] = mnew;
          lr[m] *= al;
#pragma unroll
          for (int d = 0; d < 4; ++d)
#pragma unroll
            for (int r = 0; r < 4; ++r) oacc[m][d][r] *= al;
        }
        float rs = 0.f;
#pragma unroll
        for (int n = 0; n < 4; ++n) {
#pragma unroll
          for (int r = 0; r < 4; ++r) {
            float p = exp2f(st[m][n][r] - mr[m]);
            st[m][n][r] = p;
            rs += p;
          }
          u32 lo = (u32)f2b(st[m][n][0]) | ((u32)f2b(st[m][n][1]) << 16);
          u32 hi = (u32)f2b(st[m][n][2]) | ((u32)f2b(st[m][n][3]) << 16);
          u32x2 pvv = {lo, hi};
          *(u32x2*)&Pwb[(m * 16 + c) * DK + (((n * 32 + g * 8) ^ sw) >> 1)] = pvv;
        }
        lr[m] += rs; // per-lane partial; reduced once in epilogue
      }
    };

    f32x4 mbv[4];
    s16x8 kA[4][2], kB[4][2], vf[2][4];
    f32x4 st[2][4];

    // prologue: tile 0
    loadk(kA, 0);
    if (ntw > 1) loadk(kB, 1);
    loadmb(mbv, 0);
    qk(kA, st);
    smax(0, 0, st, mbv);

    auto iter = [&](s16x8(&kc)[4][2], s16x8(&kn)[4][2], int t) {
      loadv(vf, t - 1);
      if (t + 1 < ntw) loadk(kn, t + 1);
      loadmb(mbv, t);
      __builtin_amdgcn_s_setprio(1);
      qk(kc, st);
      pv((t - 1) & 1, vf); // P(t-1) from LDS (written last iter), V(t-1)
      __builtin_amdgcn_s_setprio(0);
      smax(t, t & 1, st, mbv);
    };

    for (int t = 1; t < ntw; t += 2) {
      iter(kB, kA, t);
      if (t + 1 < ntw) iter(kA, kB, t + 1);
    }
    // flush last PV
    loadv(vf, ntw - 1);
    pv((ntw - 1) & 1, vf);

    // ---- epilogue: reduce l, normalize + store; O rows are q = wq0+m*16+g*4+r
#pragma unroll
    for (int m = 0; m < 2; ++m) {
      float rs = lr[m];
      rs += __shfl_xor(rs, 16);
      rs += __shfl_xor(rs, 32);
      float lT[4];
#pragma unroll
      for (int r = 0; r < 4; ++r) lT[r] = __shfl(rs, (g << 2) + r);
#pragma unroll
      for (int r = 0; r < 4; ++r) {
        float inv = lT[r] > 0.f ? 1.f / lT[r] : 0.f;
#pragma unroll
        for (int d = 0; d < 4; ++d) {
          size_t idx = (size_t)(b * N_ + wq0 + m * 16 + g * 4 + r) * D_MODEL + h * DK + d * 16 + c;
          Out[idx] = f2b(oacc[m][d][r] * inv);
        }
      }
    }
  }
}

extern "C" void kernel_launch(void* const* d_in, const int* in_sizes, int n_in,
                              void* d_out, int out_size, void* d_ws, size_t ws_size,
                              hipStream_t stream) {
  const float* q = (const float*)d_in[0];
  const float* k = (const float*)d_in[1];
  const float* v = (const float*)d_in[2];
  const int* mask = (const int*)d_in[3];
  const float* Wq = (const float*)d_in[4];
  const float* Wk = (const float*)d_in[5];
  const float* Wv = (const float*)d_in[6];
  const float* Wo = (const float*)d_in[7];
  float* out = (float*)d_out;

  char* ws = (char*)d_ws;
  const size_t SZ = (size_t)M_TOT * D_MODEL * 2; // 16 MiB per bf16 [8192,1024]
  u16* qb = (u16*)ws;
  u16* kb = (u16*)(ws + SZ);
  u16* vb = (u16*)(ws + 2 * SZ);
  u16* Qp = (u16*)(ws + 3 * SZ);
  u16* Kp = (u16*)(ws + 4 * SZ);
  u16* Wqt = (u16*)(ws + 5 * SZ);
  u16* Wkt = Wqt + 1024 * 1024;
  u16* Wvt = Wkt + 1024 * 1024;
  u16* Wot = Wvt + 1024 * 1024;
  float* Mb = (float*)(Wot + 1024 * 1024);
  // aliases (lifetime-disjoint):
  u16* attn_out = qb; // qb dead after Q GEMM
  u16* Vp = kb;       // kb dead after K GEMM
  u16* Vt = vb;       // vb dead after V GEMM

  int n4 = M_TOT * D_MODEL / 4;
  cvt_f32_bf16<<<n4 / 256, 256, 0, stream>>>(q, qb, n4);
  cvt_f32_bf16<<<n4 / 256, 256, 0, stream>>>(k, kb, n4);
  cvt_f32_bf16<<<n4 / 256, 256, 0, stream>>>(v, vb, n4);
  mask_bias<<<(B_ * N_ + 255) / 256, 256, 0, stream>>>(mask, Mb, B_ * N_);
  dim3 wg(32, 32);
  wtrans<<<wg, 256, 0, stream>>>(Wq, Wqt);
  wtrans<<<wg, 256, 0, stream>>>(Wk, Wkt);
  wtrans<<<wg, 256, 0, stream>>>(Wv, Wvt);
  wtrans<<<wg, 256, 0, stream>>>(Wo, Wot);
  dim3 gg(D_MODEL / 128, M_TOT / 128);
  gemm_bt<false><<<gg, 256, 0, stream>>>(qb, Wqt, nullptr, Qp, M_TOT, D_MODEL, D_MODEL);
  gemm_bt<false><<<gg, 256, 0, stream>>>(kb, Wkt, nullptr, Kp, M_TOT, D_MODEL, D_MODEL);
  gemm_bt<false><<<gg, 256, 0, stream>>>(vb, Wvt, nullptr, Vp, M_TOT, D_MODEL, D_MODEL);
  vtrans<<<dim3(N_ / 64, NHEAD, B_), 256, 0, stream>>>(Vp, Vt);
  attn_fwd<<<512, 256, 0, stream>>>(Qp, Kp, Vt, Mb, attn_out);
  gemm_bt<true><<<gg, 256, 0, stream>>>(attn_out, Wot, out, nullptr, M_TOT, D_MODEL, D_MODEL);
}